// Round 2
// baseline (1014.482 us; speedup 1.0000x reference)
//
#include <hip/hip_runtime.h>

// SparseConv2D on MI355X (gfx950), round 2 (resubmit — round 1 bench hit a
// GPU-broker acquisition timeout; no counters were produced).
// Collapsed valid 3x3 conv:
//   out[n,r,c,co] = active[n,r/14,c/14] * (bias[co] +
//       sum_{dr,dc,ci} x[n,r+dr,c+dc,ci] * K[dr,dc,ci,co]),  r,c in [0,504)
//
// Previous kernel was LDS-broadcast-bound: 32 co-lanes re-read the same x row
// from LDS (LDS pipe ~60-85% busy on 32x-redundant data) and pulled kern from
// global in the inner loop.  This version flips the broadcast axis:
//   - thread = one output position, 32 co accumulators in VGPRs
//   - x reads from LDS are per-lane distinct (72 ds_read_b128 / thread)
//   - kern index is wave-uniform -> compiler scalarizes to s_load, and the
//     inner loop is v_fmac_f32 acc, s_k, v_x  (SGPR k operand, free pipe)
//   - per-tile mask flags precomputed into workspace by a tiny kernel

#define NN    8
#define HH    506
#define WW    506
#define CIN   32
#define COUT  32
#define OH    504
#define OW    504
#define NBH   36
#define NBW   36

// ---------------- flag precompute: active[n][bh][bw] ----------------
__global__ __launch_bounds__(256) void mask_flags_kernel(
    const float* __restrict__ mask, float* __restrict__ flags)
{
    __shared__ float sred[4];
    const int bw = blockIdx.x, bh = blockIdx.y, n = blockIdx.z;
    const int t = threadIdx.x;
    const int i = t >> 4, j = t & 15;           // 16x16 window at stride-14 grid
    float m = mask[(size_t)(n * HH + bh * 14 + i) * WW + (bw * 14 + j)];
    #pragma unroll
    for (int off = 32; off > 0; off >>= 1)
        m = fmaxf(m, __shfl_down(m, off, 64));
    if ((t & 63) == 0) sred[t >> 6] = m;
    __syncthreads();
    if (t == 0) {
        const float mm = fmaxf(fmaxf(sred[0], sred[1]), fmaxf(sred[2], sred[3]));
        flags[(n * NBH + bh) * NBW + bw] = (mm > 0.5f) ? 1.0f : 0.0f;
    }
}

// ---------------- main conv: 16x16 output region per block ----------------
#define TO 16                    // output tile edge
#define TI 18                    // input tile edge (TO + 2)
#define PS 36                    // LDS position stride in floats (32 + 4 pad)
                                 // -> 144 B: 16B-aligned, 4c+j bank pattern
                                 //    gives the 2-addr/bank minimum for b128

__global__ __launch_bounds__(256) void conv16_kernel(
    const float* __restrict__ x, const float* __restrict__ kern,
    const float* __restrict__ bias, const float* __restrict__ flags,
    float* __restrict__ out)
{
    __shared__ float xs[TI * TI * PS];          // 46656 B -> 3 blocks/CU

    const int bx = blockIdx.x, by = blockIdx.y, n = blockIdx.z;
    const int R0 = by * TO, C0 = bx * TO;
    const int t = threadIdx.x;

    // stage 18x18x32 input tile, NHWC order, padded position stride.
    // 2592 float4 loads, contiguous 2.25 KB runs per input row.
    for (int q = t; q < TI * TI * 8; q += 256) {
        const int row = q / (TI * 8);
        const int rem = q - row * (TI * 8);
        const int c = rem >> 3, g = rem & 7;
        const int gr = min(R0 + row, HH - 1);   // clamp: edge blocks, values unused
        const int gc = min(C0 + c, WW - 1);
        const float4 v = *(const float4*)(
            x + ((size_t)(n * HH + gr) * WW + gc) * CIN + g * 4);
        *(float4*)&xs[(row * TI + c) * PS + g * 4] = v;
    }
    __syncthreads();

    const int i = t >> 4, j = t & 15;           // quarter-wave = one row, c 0..15

    float acc[COUT];
    #pragma unroll
    for (int co = 0; co < COUT; ++co) acc[co] = 0.0f;

    #pragma unroll 1                            // keep body ~1024 FMA: fits I$
    for (int dr = 0; dr < 3; ++dr) {
        #pragma unroll 1
        for (int dc = 0; dc < 3; ++dc) {
            // per-lane-distinct x vector: 8x ds_read_b128, conflict-minimal
            const float4* xp = (const float4*)&xs[((i + dr) * TI + (j + dc)) * PS];
            float xv[CIN];
            #pragma unroll
            for (int g = 0; g < 8; ++g) {
                const float4 v = xp[g];
                xv[g * 4 + 0] = v.x; xv[g * 4 + 1] = v.y;
                xv[g * 4 + 2] = v.z; xv[g * 4 + 3] = v.w;
            }
            // kern index is thread-invariant -> s_load (scalar cache),
            // FMAs take k from SGPR: no VMEM, no LDS in the hot loop.
            const float* kp = kern + (dr * 3 + dc) * (CIN * COUT);
            #pragma unroll
            for (int ci = 0; ci < CIN; ++ci) {
                const float xc = xv[ci];
                #pragma unroll
                for (int co = 0; co < COUT; ++co)
                    acc[co] = fmaf(xc, kp[ci * COUT + co], acc[co]);
            }
        }
    }

    const int r = R0 + i, c = C0 + j;
    if (r < OH && c < OW) {
        const float flag = flags[((size_t)n * NBH + r / 14) * NBW + c / 14];
        float* op = out + ((size_t)(n * OH + r) * OW + c) * COUT;
        #pragma unroll
        for (int g = 0; g < 8; ++g) {
            float4 v;
            v.x = (acc[g * 4 + 0] + bias[g * 4 + 0]) * flag;
            v.y = (acc[g * 4 + 1] + bias[g * 4 + 1]) * flag;
            v.z = (acc[g * 4 + 2] + bias[g * 4 + 2]) * flag;
            v.w = (acc[g * 4 + 3] + bias[g * 4 + 3]) * flag;
            *(float4*)(op + g * 4) = v;
        }
    }
}

extern "C" void kernel_launch(void* const* d_in, const int* in_sizes, int n_in,
                              void* d_out, int out_size, void* d_ws, size_t ws_size,
                              hipStream_t stream) {
    const float* x    = (const float*)d_in[0];
    const float* mask = (const float*)d_in[1];
    const float* kern = (const float*)d_in[2];
    const float* bias = (const float*)d_in[3];
    float* out        = (float*)d_out;
    float* flags      = (float*)d_ws;          // 8*36*36 floats = 41.5 KB

    dim3 gridA(NBW, NBH, NN);                  // 36 x 36 x 8 tiles
    mask_flags_kernel<<<gridA, 256, 0, stream>>>(mask, flags);

    dim3 gridB((OW + TO - 1) / TO, (OH + TO - 1) / TO, NN);  // 32 x 32 x 8
    conv16_kernel<<<gridB, 256, 0, stream>>>(x, kern, bias, flags, out);
}